// Round 5
// baseline (571.535 us; speedup 1.0000x reference)
//
#include <hip/hip_runtime.h>
#include <hip/hip_bf16.h>
#include <math.h>

#define BATCH 4
#define NHEADS 16
#define SEQ 2048
#define HDIM 128
#define NPAT 4

#define BM 128
#define BN 64
#define NTHREADS 256
#define NKT (SEQ / BN)          // 32 kv-tiles per (b,h)
#define TILE_BYTES 16384        // K tile: 64 rows x 256B ; V^T tile: 128 rows x 128B
#define NBLOCKS (BATCH * NHEADS * (SEQ / BM))   // 1024

typedef _Float16 f16x8 __attribute__((ext_vector_type(8)));
typedef _Float16 f16x4 __attribute__((ext_vector_type(4)));
typedef float floatx4 __attribute__((ext_vector_type(4)));

typedef const __attribute__((address_space(1))) void gvoid_t;
typedef __attribute__((address_space(3))) void lvoid_t;

// raw v_exp_f32 (exp2). OCML exp2f == v_exp_f32 + subnormal-result fixup; our
// P_MIN clamp (2^-14) makes the fixup unobservable -> bit-identical outcomes.
#if __has_builtin(__builtin_amdgcn_exp2f)
#define EXP2(x) __builtin_amdgcn_exp2f(x)
#else
#define EXP2(x) exp2f(x)
#endif

// ---------------- selector: per-head pattern argmax (+ used-pattern flags) ----
__global__ void sel_kernel(const float* __restrict__ w1, const float* __restrict__ b1,
                           const float* __restrict__ w2, const float* __restrict__ b2,
                           int* __restrict__ pat_idx, int* __restrict__ used) {
  int h = threadIdx.x;
  if (h < NPAT) used[h] = 0;
  __syncthreads();
  if (h >= NHEADS) return;
  float f0 = 1.0f;               // S / MAX_SEQ_LEN = 2048/2048
  float f1 = (float)h / 12.0f;
  float f2 = 0.5f;
  float acc[NPAT] = {b2[0], b2[1], b2[2], b2[3]};
  for (int j = 0; j < 32; ++j) {
    float hj = f0 * w1[j] + f1 * w1[32 + j] + f2 * w1[64 + j] + b1[j];
    hj = fmaxf(hj, 0.0f);
    for (int p = 0; p < NPAT; ++p) acc[p] += hj * w2[j * NPAT + p];
  }
  int best = 0;
  float bv = acc[0];
  for (int p = 1; p < NPAT; ++p) {
    if (acc[p] > bv) { bv = acc[p]; best = p; }   // strict > : first-max like jnp.argmax
  }
  pat_idx[h] = best;
  atomicOr(&used[best], 1);
}

// ---------------- binarize pattern masks to bit words ----------------
// Reference does sigmoid(x) > 0.5 IN FP32; exact-rounding window only matters
// for |x| < ~1e-5: there fp32 sigmoid can round to exactly 0.5 (-> false),
// unlike sign(x). __noinline__ call + ballot guard keeps the f64-exp path
// off the speculated fast path. Bit-exact vs reference.
__device__ __attribute__((noinline)) bool sig_gt_half_slow(float x) {
  float t = (float)exp(-(double)x);   // correctly-rounded fp32 exp(-x)
  float s = 1.0f / (1.0f + t);        // fp32 IEEE add + div
  return s > 0.5f;
}

__global__ void bin_kernel(const float* __restrict__ pm, unsigned int* __restrict__ bits,
                           const int* __restrict__ used) {
  int pat = blockIdx.x >> 9;                      // 512 blocks per pattern
  if (!used[pat]) return;
  int t = blockIdx.x * blockDim.x + threadIdx.x;  // one 32-col word per thread
  const float4* s4 = (const float4*)(pm + (size_t)t * 32);
  unsigned int w = 0;
  bool anyneed = false;
#pragma unroll
  for (int i = 0; i < 8; ++i) {
    float4 v = s4[i];
    float e[4] = {v.x, v.y, v.z, v.w};
#pragma unroll
    for (int j = 0; j < 4; ++j) {
      anyneed |= (fabsf(e[j]) < 1e-5f);
      w |= ((e[j] > 0.0f) ? 1u : 0u) << (i * 4 + j);
    }
  }
  if (__ballot(anyneed)) {        // wave-uniform guard: slow re-walk is rare
    if (anyneed) {                // divergent; calls are exec-masked, not speculated
      w = 0;
#pragma unroll 1
      for (int i = 0; i < 8; ++i) {
        float4 v = s4[i];
        float e[4] = {v.x, v.y, v.z, v.w};
        for (int j = 0; j < 4; ++j) {
          bool b = (fabsf(e[j]) < 1e-5f) ? sig_gt_half_slow(e[j]) : (e[j] > 0.0f);
          w |= (b ? 1u : 0u) << (i * 4 + j);
        }
      }
    }
  }
  bits[t] = w;
}

// ---------------- preprocess K: fp32 -> fp16 swizzled tiles ----------------
// Kp tile layout (16KB per (bh,kt)): byte o holds K[tile*64 + r][c] fp16 where
// r = o>>8, c = ((o&255) ^ ((r&7)<<4)) >> 1.  flash stages this linearly via
// global_load_lds and reads fragments at byte r*256 + (colbyte ^ ((r&7)<<4))
// -> conflict-free ds_read_b128.
__global__ __launch_bounds__(256) void prep_k(const float* __restrict__ K,
                                              _Float16* __restrict__ Kp) {
  size_t q0 = ((size_t)blockIdx.x * 256 + threadIdx.x) * 16;  // output byte
  int tile = (int)(q0 >> 14);
  int p = (int)(q0 & 16383);
  int r = p >> 8;
  int cb = (p & 255) ^ ((r & 7) << 4);
  const float* src = K + ((size_t)tile * 64 + r) * HDIM + (cb >> 1);
  float4 a = ((const float4*)src)[0];
  float4 b = ((const float4*)src)[1];
  f16x8 f;
  f[0] = (_Float16)a.x; f[1] = (_Float16)a.y; f[2] = (_Float16)a.z; f[3] = (_Float16)a.w;
  f[4] = (_Float16)b.x; f[5] = (_Float16)b.y; f[6] = (_Float16)b.z; f[7] = (_Float16)b.w;
  *(f16x8*)((char*)Kp + q0) = f;
}

// ---------------- preprocess V: LDS-transposed fp16 tiles -------------------
// Vt tile (16KB per (bh,kt)) = V^T [d=128][kc-slot], both sides coalesced via
// an LDS tile transpose. kc-slot ordering bakes BOTH the XOR-16B swizzle and
// the in-register P-exchange permutation used by flash's PV step:
//   chunk c' at row d holds logical chunk clog = c' ^ (d&7); q=clog&3, ks=clog>>2
//   slot j in chunk -> kc = ((q>>1)*2+ks)*16 + (j<4 ? q : q^2)*4 + (j&3)
__global__ __launch_bounds__(256) void prep_vt(const float* __restrict__ V,
                                               _Float16* __restrict__ Vt) {
  __shared__ _Float16 tile[64][140];   // pitch 140 f16 = 280B (8B-aligned, bank-spread)
  const int t = threadIdx.x;
  const float* vsrc = V + (size_t)blockIdx.x * 64 * HDIM;
#pragma unroll
  for (int i = 0; i < 8; ++i) {
    int idx = i * 256 + t;             // 2048 float4 chunks: row kc, 32 chunks/row
    int kc = idx >> 5, c4 = idx & 31;
    float4 v = ((const float4*)(vsrc + kc * HDIM))[c4];
    f16x4 f;
    f[0] = (_Float16)v.x; f[1] = (_Float16)v.y; f[2] = (_Float16)v.z; f[3] = (_Float16)v.w;
    *(f16x4*)&tile[kc][c4 * 4] = f;
  }
  __syncthreads();
  char* dst = (char*)Vt + (size_t)blockIdx.x * TILE_BYTES;
#pragma unroll
  for (int i = 0; i < 4; ++i) {
    int p = (i * 256 + t) * 16;        // output byte in tile
    int d = p >> 7;
    int cp = (p & 127) >> 4;
    int clog = cp ^ (d & 7);
    int q = clog & 3, ks = clog >> 2;
    int T16 = ((q >> 1) * 2 + ks) << 4;
    f16x8 f;
#pragma unroll
    for (int j = 0; j < 8; ++j) {
      int qsel = (j < 4) ? q : (q ^ 2);
      int kc = T16 + qsel * 4 + (j & 3);
      f[j] = tile[kc][d];
    }
    *(f16x8*)(dst + p) = f;
  }
}

// ---------------- flash attention with multiplicative binary mask ----------------
// 3-blocks/CU schedule: single K buffer + double-buffered V/masks (51200 B LDS).
// Per iter: QK^T(kbuf) -> barrier1 (drains only lgkm; no loads in flight) ->
// stage K/V/masks(t+1) -> softmax -> PV(vbuf[cur]) -> barrier2 (drains the
// prefetch after ~1000cy of compute). l-reduction deferred to epilogue
// (per-lane partials; alpha is row-uniform so rescale commutes).
__global__ __launch_bounds__(NTHREADS, 3) void flash_kernel(
    const float* __restrict__ Q, const _Float16* __restrict__ Kp,
    const _Float16* __restrict__ Vt, const unsigned int* __restrict__ bits,
    const int* __restrict__ pat_idx, float* __restrict__ out) {
  __shared__ alignas(16) char kbuf_raw[TILE_BYTES];       // K tile (single buffer)
  __shared__ alignas(16) char vbuf_raw[2][TILE_BYTES];    // V^T tiles (double)
  __shared__ unsigned int maskw[2][BM][2];

  const int tid = threadIdx.x;
  const int wave = tid >> 6;
  const int lane = tid & 63;
  const int l16 = lane & 15;
  const int quad = lane >> 4;
  const int swz = l16 & 7;

  // bijective XCD chunk swizzle
  int bid = (int)blockIdx.x;
  bid = (bid & 7) * (NBLOCKS / 8) + (bid >> 3);
  const int bh = bid >> 4;       // 0..63 = b*16+h
  const int qt = bid & 15;
  const int h = bh & (NHEADS - 1);
  const int qbase = qt * BM;
  const int pat = pat_idx[h];

  const float SCL = 0.08838834764831845f * 1.4426950408889634f;  // rsqrt(128)*log2(e)
  const float P_MIN = 6.103515625e-05f;  // 2^-14: fp16 normal floor; below -> 0

  const unsigned int* bits_p = bits + ((size_t)pat * SEQ + qbase) * (SEQ / 32);
  // per-lane staging bases (hoisted)
  const char* kgbase = (const char*)Kp + (size_t)bh * NKT * TILE_BYTES + wave * 1024 + lane * 16;
  const char* vgbase = (const char*)Vt + (size_t)bh * NKT * TILE_BYTES + wave * 1024 + lane * 16;
  const unsigned int* mgbase = bits_p + (size_t)(wave * 32 + (lane >> 1)) * (SEQ / 32) + (lane & 1);

  auto stage_k = [&](int kt) {
    const char* kgt = kgbase + (size_t)kt * TILE_BYTES;
    char* kl = kbuf_raw + wave * 1024;
#pragma unroll
    for (int i = 0; i < 4; ++i)
      __builtin_amdgcn_global_load_lds((gvoid_t*)(kgt + i * 4096),
                                       (lvoid_t*)(kl + i * 4096), 16, 0, 0);
  };
  auto stage_v = [&](int nb, int kt) {
    const char* vgt = vgbase + (size_t)kt * TILE_BYTES;
    char* vl = &vbuf_raw[nb][0] + wave * 1024;
#pragma unroll
    for (int i = 0; i < 4; ++i)
      __builtin_amdgcn_global_load_lds((gvoid_t*)(vgt + i * 4096),
                                       (lvoid_t*)(vl + i * 4096), 16, 0, 0);
    // mask words: rows wave*32..wave*32+31, 2 words each -> lane*4 linear dest
    __builtin_amdgcn_global_load_lds((gvoid_t*)(mgbase + 2 * kt),
                                     (lvoid_t*)&maskw[nb][wave * 32][0], 4, 0, 0);
  };

  // prologue: stage tile 0 (DMA in flight while we build Q fragments)
  stage_k(0);
  stage_v(0, 0);

  // Q fragments: B-operand of swapped QK^T, B[k=quad*8+j (d)][n=l16 (qrow)]
  f16x8 qf[2][4];
#pragma unroll
  for (int mt = 0; mt < 2; ++mt) {
    const int row = qbase + wave * 32 + mt * 16 + l16;
    const float* qp = Q + ((size_t)bh * SEQ + row) * HDIM;
#pragma unroll
    for (int ks = 0; ks < 4; ++ks) {
      const float4* p4 = (const float4*)(qp + ks * 32 + quad * 8);
      float4 a = p4[0], c = p4[1];
      f16x8 f;
      f[0] = (_Float16)a.x; f[1] = (_Float16)a.y; f[2] = (_Float16)a.z; f[3] = (_Float16)a.w;
      f[4] = (_Float16)c.x; f[5] = (_Float16)c.y; f[6] = (_Float16)c.z; f[7] = (_Float16)c.w;
      qf[mt][ks] = f;
    }
  }

  floatx4 o_acc[2][8];
#pragma unroll
  for (int mt = 0; mt < 2; ++mt)
#pragma unroll
    for (int n = 0; n < 8; ++n) o_acc[mt][n] = (floatx4){0.f, 0.f, 0.f, 0.f};
  float m_run[2] = {-INFINITY, -INFINITY};   // per-lane: qrow = mt*16 + l16
  float l_run[2] = {0.0f, 0.0f};             // per-lane PARTIAL (reduced in epilogue)

  __syncthreads();   // tile 0 resident
  int cur = 0;

  for (int kt = 0; kt < NKT; ++kt) {
    // ---- S^T = K @ Q^T : sf[t][mt], C-layout row = kcol-in-tile, col = qrow ----
    floatx4 sf[4][2];
#pragma unroll
    for (int t = 0; t < 4; ++t)
#pragma unroll
      for (int mt = 0; mt < 2; ++mt) sf[t][mt] = (floatx4){0.f, 0.f, 0.f, 0.f};
    __builtin_amdgcn_s_setprio(1);
#pragma unroll
    for (int t = 0; t < 4; ++t) {
      const char* krow = kbuf_raw + ((t * 16 + l16) << 8);
#pragma unroll
      for (int ks = 0; ks < 4; ++ks) {
        f16x8 kf = *(const f16x8*)(krow + ((((ks << 2) | quad) ^ swz) << 4));
#pragma unroll
        for (int mt = 0; mt < 2; ++mt)
          sf[t][mt] = __builtin_amdgcn_mfma_f32_16x16x32_f16(kf, qf[mt][ks], sf[t][mt], 0, 0, 0);
      }
    }
    __builtin_amdgcn_s_setprio(0);

    __syncthreads();   // barrier1: all waves done reading kbuf (drains lgkm only)

    // prefetch tile t+1: K into the single kbuf, V/masks into the other buffer.
    // Latency hides under softmax+PV (~1000cy); drained at barrier2.
    if (kt + 1 < NKT) {
      stage_k(kt + 1);
      stage_v(cur ^ 1, kt + 1);
    }

    // ---- mask (multiplicative) + row max, lane-local row = l16 ----
#pragma unroll
    for (int mt = 0; mt < 2; ++mt) {
      const int rl = wave * 32 + mt * 16 + l16;
      const unsigned w0 = maskw[cur][rl][0], w1 = maskw[cur][rl][1];
#pragma unroll
      for (int t = 0; t < 4; ++t) {
        const unsigned wd = (t & 2) ? w1 : w0;
        const int base = ((t & 1) << 4) + (quad << 2);  // kcol&31 = (t&1)*16+quad*4+r
#pragma unroll
        for (int r = 0; r < 4; ++r) {
          float s = sf[t][mt][r];
          sf[t][mt][r] = ((wd >> (base + r)) & 1u) ? s * SCL : 0.0f;
        }
      }
    }
    float mx0 = sf[0][0][0], mx1 = sf[0][1][0];
#pragma unroll
    for (int t = 0; t < 4; ++t)
#pragma unroll
      for (int r = 0; r < 4; ++r) {
        mx0 = fmaxf(mx0, sf[t][0][r]);
        mx1 = fmaxf(mx1, sf[t][1][r]);
      }
    mx0 = fmaxf(mx0, __shfl_xor(mx0, 16));
    mx0 = fmaxf(mx0, __shfl_xor(mx0, 32));
    mx1 = fmaxf(mx1, __shfl_xor(mx1, 16));
    mx1 = fmaxf(mx1, __shfl_xor(mx1, 32));

    // ---- THR=0 defer-max: skip the exp2(0)=1.0 rescale when max unchanged ----
    if (!__all((mx0 <= m_run[0]) && (mx1 <= m_run[1]))) {
      float alpha[2];
      const float mn0 = fmaxf(m_run[0], mx0);
      const float mn1 = fmaxf(m_run[1], mx1);
      alpha[0] = EXP2(m_run[0] - mn0);   // first iter: exp2(-inf)=0
      alpha[1] = EXP2(m_run[1] - mn1);
      m_run[0] = mn0; m_run[1] = mn1;
      l_run[0] *= alpha[0]; l_run[1] *= alpha[1];   // per-lane partial, row-uniform alpha
#pragma unroll
      for (int mt = 0; mt < 2; ++mt) {
#pragma unroll
        for (int r = 0; r < 4; ++r) {
          const float ac = __shfl(alpha[mt], (quad << 2) | r, 16);
#pragma unroll
          for (int n = 0; n < 8; ++n) o_acc[mt][n][r] *= ac;
        }
      }
    }

    // ---- P = exp2(S - m), quantize-first, accumulate per-lane partial of l ----
    f16x4 hq[4][2];          // quantized P, per (kcol-tile, mt)
#pragma unroll
    for (int mt = 0; mt < 2; ++mt) {
      const float mrow = m_run[mt];
      float ps = 0.0f;
#pragma unroll
      for (int t = 0; t < 4; ++t) {
#pragma unroll
        for (int r = 0; r < 4; ++r) {
          float p = EXP2(sf[t][mt][r] - mrow);
          if (p < P_MIN) p = 0.0f;            // stay out of fp16 subnormals
          _Float16 hh = (_Float16)p;          // quantize FIRST...
          hq[t][mt][r] = hh;
          ps += (float)hh;                    // ...then sum: l matches MFMA weights
        }
      }
      l_run[mt] += ps;                        // cross-lane reduce deferred to epilogue
    }

    // ---- P: C->A layout fully in-register ----
    __builtin_amdgcn_s_setprio(1);
#pragma unroll
    for (int ks = 0; ks < 2; ++ks) {
      f16x8 pa[2];
#pragma unroll
      for (int mt = 0; mt < 2; ++mt) {
        f16x4 hk = (quad & 2) ? hq[ks + 2][mt] : hq[ks][mt];   // keep: own consumed tile
        f16x4 hs = (quad & 2) ? hq[ks][mt] : hq[ks + 2][mt];   // send: partner's tile
        union { f16x4 v; unsigned u[2]; } K_, S_;
        K_.v = hk; S_.v = hs;
        unsigned p0 = (unsigned)__shfl_xor((int)S_.u[0], 32);
        unsigned p1 = (unsigned)__shfl_xor((int)S_.u[1], 32);
        union { unsigned u[4]; f16x8 v; } P_;
        P_.u[0] = K_.u[0]; P_.u[1] = K_.u[1]; P_.u[2] = p0; P_.u[3] = p1;
        pa[mt] = P_.v;
      }
#pragma unroll
      for (int nt = 0; nt < 8; ++nt) {
        const char* vrow = &vbuf_raw[cur][0] + ((nt * 16 + l16) << 7);
        f16x8 vb = *(const f16x8*)(vrow + ((((ks << 2) | quad) ^ swz) << 4));
#pragma unroll
        for (int mt = 0; mt < 2; ++mt)
          o_acc[mt][nt] = __builtin_amdgcn_mfma_f32_16x16x32_f16(pa[mt], vb, o_acc[mt][nt], 0, 0, 0);
      }
    }
    __builtin_amdgcn_s_setprio(0);

    __syncthreads();   // barrier2: drains prefetch; joins vbuf reads; buffers flip
    cur ^= 1;
  }

  // ---- epilogue: finish l reduction, then O / l ----
#pragma unroll
  for (int mt = 0; mt < 2; ++mt) {
    l_run[mt] += __shfl_xor(l_run[mt], 16);
    l_run[mt] += __shfl_xor(l_run[mt], 32);
  }
#pragma unroll
  for (int mt = 0; mt < 2; ++mt) {
#pragma unroll
    for (int r = 0; r < 4; ++r) {
      const float lv = __shfl(l_run[mt], (quad << 2) | r, 16);
      const float inv = 1.0f / lv;
      const int row = qbase + wave * 32 + mt * 16 + quad * 4 + r;
      float* og = out + ((size_t)bh * SEQ + row) * HDIM + l16;
#pragma unroll
      for (int n = 0; n < 8; ++n) og[n * 16] = o_acc[mt][n][r] * inv;
    }
  }
}

extern "C" void kernel_launch(void* const* d_in, const int* in_sizes, int n_in,
                              void* d_out, int out_size, void* d_ws, size_t ws_size,
                              hipStream_t stream) {
  const float* Q  = (const float*)d_in[0];
  const float* K  = (const float*)d_in[1];
  const float* V  = (const float*)d_in[2];
  const float* pm = (const float*)d_in[3];
  const float* w1 = (const float*)d_in[4];
  const float* b1 = (const float*)d_in[5];
  const float* w2 = (const float*)d_in[6];
  const float* b2 = (const float*)d_in[7];
  float* out = (float*)d_out;

  // workspace layout (16B-aligned):
  //   [0,256)            pat_idx (16 ints)
  //   [256,512)          used-pattern flags (4 ints)
  //   [4096, +2MB)       mask bit words
  //   [+0, +32MB)        Kp fp16 swizzled tiles
  //   [+32MB, +64MB)     Vt fp16 transposed swizzled tiles
  int* pat_idx = (int*)d_ws;
  int* used = (int*)((char*)d_ws + 256);
  unsigned int* bits = (unsigned int*)((char*)d_ws + 4096);
  _Float16* Kp = (_Float16*)((char*)d_ws + 4096 + 2097152);
  _Float16* Vt = (_Float16*)((char*)d_ws + 4096 + 2097152 + 33554432);

  sel_kernel<<<1, 64, 0, stream>>>(w1, b1, w2, b2, pat_idx, used);
  bin_kernel<<<(NPAT * SEQ * (SEQ / 32)) / 256, 256, 0, stream>>>(pm, bits, used);
  prep_k<<<(BATCH * NHEADS * NKT * 1024) / 256, 256, 0, stream>>>(K, Kp);
  prep_vt<<<BATCH * NHEADS * NKT, 256, 0, stream>>>(V, Vt);
  flash_kernel<<<NBLOCKS, NTHREADS, 0, stream>>>(Q, Kp, Vt, bits, pat_idx, out);
}